// Round 2
// baseline (173.928 us; speedup 1.0000x reference)
//
#include <hip/hip_runtime.h>

// SelfAttention3D: B=4, C=128, N=16^3=4096, Cqk=16.
// R6: occupancy fix. R5's 512x8-wave blocks (acc[16], 124 VGPR) cap at
// 16 waves/CU. Restructure attn: 1024 blocks x 512 threads, 16 queries
// per block; wave (kg,cg) = key-half x channel-quarter. Per 64-key tile:
// wave produces P for its 16-key slice (1 QK MFMA + 4 exp -> shared LDS
// P, double-buffered), one barrier, then consumes full P vs its 32 V
// channels (4 PV MFMA). acc[2]=8 VGPR -> launch_bounds(512,8) (64-reg
// cap) -> 4 blocks/CU = 32 waves/CU. LDS 66.5KB -> 9.7KB.

typedef __attribute__((ext_vector_type(8))) short short8;
typedef __attribute__((ext_vector_type(4))) float f32x4;

#define NTOK 4096
#define CDIM 128

__device__ __forceinline__ unsigned short f2bf(float f) {
  unsigned int u = __float_as_uint(f);
  return (unsigned short)((u + 0x7fffu + ((u >> 16) & 1u)) >> 16);
}

// ---------------------------------------------------------------------------
// Projection (unchanged from R5): q,k,v channel-GEMMs, bf16 outputs.
// qb,kb: [B][N][16] row per token; vb: tiled layout (see attn).
// ---------------------------------------------------------------------------
__global__ __launch_bounds__(256) void sa3d_proj(
    const float* __restrict__ x,
    const float* __restrict__ Wq, const float* __restrict__ bq,
    const float* __restrict__ Wk, const float* __restrict__ bk,
    const float* __restrict__ Wv, const float* __restrict__ bv,
    unsigned short* __restrict__ qb, unsigned short* __restrict__ kb,
    unsigned short* __restrict__ vb)
{
  __shared__ unsigned short Wl[160 * 136];
  __shared__ unsigned short xT[64 * 136];
  const int tid = threadIdx.x;
  const int b = (blockIdx.x & 7) >> 1;
  const int nt = ((blockIdx.x >> 3) << 1) | (blockIdx.x & 1);  // [0,64)
  const int n0 = nt << 6;

  for (int i = 0; i < 80; ++i) {
    int idx = i * 256 + tid;
    int o = idx >> 7, c = idx & 127;
    float wv;
    if (o < 16)      wv = Wq[o * 128 + c];
    else if (o < 32) wv = Wk[(o - 16) * 128 + c];
    else             wv = Wv[(o - 32) * 128 + c];
    Wl[o * 136 + c] = f2bf(wv);
  }
  {
    int nn = tid & 63, cg = tid >> 6;
    const float* xp = x + (size_t)b * CDIM * NTOK + n0 + nn;
    for (int cp = 0; cp < 16; ++cp) {
      int c = cg * 32 + cp * 2;
      float v0 = xp[(size_t)c * NTOK];
      float v1 = xp[(size_t)(c + 1) * NTOK];
      *(unsigned int*)&xT[nn * 136 + c] =
          (unsigned int)f2bf(v0) | ((unsigned int)f2bf(v1) << 16);
    }
  }
  __syncthreads();

  const int w = tid >> 6, lane = tid & 63;
  const int l15 = lane & 15, g = lane >> 4;

  short8 bfr[4];
#pragma unroll
  for (int ks = 0; ks < 4; ++ks)
    bfr[ks] = *(const short8*)&xT[(w * 16 + l15) * 136 + ks * 32 + g * 8];

  const int n = n0 + w * 16 + l15;
#pragma unroll
  for (int ot = 0; ot < 10; ++ot) {
    f32x4 acc = {};
#pragma unroll
    for (int ks = 0; ks < 4; ++ks) {
      short8 af = *(const short8*)&Wl[(ot * 16 + l15) * 136 + ks * 32 + g * 8];
      acc = __builtin_amdgcn_mfma_f32_16x16x32_bf16(af, bfr[ks], acc, 0, 0, 0);
    }
    int ob = ot * 16 + 4 * g;
    if (ot == 0) {
      unsigned int p0 = (unsigned int)f2bf(acc[0] + bq[ob]) |
                        ((unsigned int)f2bf(acc[1] + bq[ob + 1]) << 16);
      unsigned int p1 = (unsigned int)f2bf(acc[2] + bq[ob + 2]) |
                        ((unsigned int)f2bf(acc[3] + bq[ob + 3]) << 16);
      unsigned int* d = (unsigned int*)&qb[((size_t)b * NTOK + n) * 16 + ob];
      d[0] = p0; d[1] = p1;
    } else if (ot == 1) {
      int o2 = ob - 16;
      unsigned int p0 = (unsigned int)f2bf(acc[0] + bk[o2]) |
                        ((unsigned int)f2bf(acc[1] + bk[o2 + 1]) << 16);
      unsigned int p1 = (unsigned int)f2bf(acc[2] + bk[o2 + 2]) |
                        ((unsigned int)f2bf(acc[3] + bk[o2 + 3]) << 16);
      unsigned int* d = (unsigned int*)&kb[((size_t)b * NTOK + n) * 16 + o2];
      d[0] = p0; d[1] = p1;
    } else {
#pragma unroll
      for (int r = 0; r < 4; ++r) {
        int o = ob + r - 32;  // channel c in [0,128)
        // tiled V: elem(c,m) = (c>>4)*65536 + (m>>5)*512 + ((m>>3)&3)*128
        //                      + (c&15)*8 + (m&7)
        size_t eidx = (size_t)(o >> 4) * 65536 + (size_t)(n >> 5) * 512 +
                      (size_t)((n >> 3) & 3) * 128 + (o & 15) * 8 + (n & 7);
        vb[(size_t)b * (CDIM * NTOK) + eidx] = f2bf(acc[r] + bv[o]);
      }
    }
  }
}

// ---------------------------------------------------------------------------
// Flash attention, producer/consumer waves.
// 1024 blocks x 512 threads. Block: batch b=(bid&7)>>1 (XCD-pinned), 16
// queries. Wave w: kg=w>>2 (keys [kg*2048,+2048), 32 tiles of 64), cg=w&3
// (channels [cg*32,+32)). Per tile: produce P slice (QK+exp -> LDS,
// 2-buffered), barrier, consume full P vs 32 V channels (reg-staged V).
// End: 2-way kg acc-reduce + 8-way L reduce; kg==0 waves do the epilogue.
// LDS: P 4x2304B = [0,9216); LDp 8x16 floats = [9216,9728);
//      reduce area reuses [0,8192) after the loop.
// ---------------------------------------------------------------------------
__global__ __launch_bounds__(512, 8) void sa3d_attn(
    const unsigned short* __restrict__ qb, const unsigned short* __restrict__ kb,
    const unsigned short* __restrict__ vb,
    const float* __restrict__ x, const float* __restrict__ gamma,
    float* __restrict__ out)
{
  __shared__ __align__(16) unsigned char smem[9728];
  unsigned short* P = (unsigned short*)smem;      // [buf(2)][kg(2)]: 16x72 shorts
  float* LDp = (float*)(smem + 9216);             // 8 waves x 16 floats

  const int tid = threadIdx.x;
  const int w = tid >> 6, lane = tid & 63;
  const int l15 = lane & 15, g = lane >> 4;
  const int kg = w >> 2, cg = w & 3;
  const int b = (blockIdx.x & 7) >> 1;
  const int qt = ((blockIdx.x >> 3) << 1) | (blockIdx.x & 1);  // [0,256)
  const int q0 = qt << 4;

  const unsigned short* qbase = qb + (size_t)b * NTOK * 16;
  const unsigned short* kbase = kb + (size_t)b * NTOK * 16;
  const unsigned short* vbase = vb + (size_t)b * CDIM * NTOK;

  short8 aq = short8{};
  if (g < 2) aq = *(const short8*)&qbase[(size_t)(q0 + l15) * 16 + g * 8];

  f32x4 acc[2];
  acc[0] = (f32x4){}; acc[1] = (f32x4){};
  float Lp[4] = {0.f, 0.f, 0.f, 0.f};

  const int kv0 = kg << 11;            // 2048 keys per kg
  const int kcol = (cg << 4) + l15;    // this wave's key-column in a 64-tile
  const int pkg = kg * 1152;           // P kg sub-offset (shorts)

  // prologue: produce tile 0 -> buf0
  {
    short8 kf = short8{};
    if (g < 2)
      kf = *(const short8*)&kbase[(size_t)(kv0 + kcol) * 16 + g * 8];
    f32x4 z = {};
    f32x4 s = __builtin_amdgcn_mfma_f32_16x16x32_bf16(aq, kf, z, 0, 0, 0);
#pragma unroll
    for (int r = 0; r < 4; ++r) {
      float e = __expf(s[r]);
      Lp[r] += e;
      P[pkg + (4 * g + r) * 72 + kcol] = f2bf(e);
    }
  }
  __syncthreads();

#pragma unroll 2
  for (int t = 0; t < 31; ++t) {
    const int bufc = t & 1, bufp = bufc ^ 1;
    const int mrow = (kv0 >> 5) + t * 2;
    // V register stage for tile t (coalesced 1KB loads, tiled layout)
    short8 vf[4];
#pragma unroll
    for (int ct2 = 0; ct2 < 2; ++ct2)
#pragma unroll
      for (int ch = 0; ch < 2; ++ch)
        vf[ct2 * 2 + ch] = *(const short8*)&vbase[
            (size_t)(cg * 2 + ct2) * 65536 + (size_t)(mrow + ch) * 512 +
            g * 128 + l15 * 8];
    // K slice for tile t+1
    short8 kf = short8{};
    if (g < 2)
      kf = *(const short8*)&kbase[
          (size_t)(kv0 + ((t + 1) << 6) + kcol) * 16 + g * 8];
    // P fragments for tile t (written before last barrier)
    short8 pa[2];
#pragma unroll
    for (int ch = 0; ch < 2; ++ch)
      pa[ch] = *(const short8*)&P[bufc * 2304 + pkg + l15 * 72 + ch * 32 + g * 8];
    // produce tile t+1 -> bufp
    {
      f32x4 z = {};
      f32x4 s = __builtin_amdgcn_mfma_f32_16x16x32_bf16(aq, kf, z, 0, 0, 0);
#pragma unroll
      for (int r = 0; r < 4; ++r) {
        float e = __expf(s[r]);
        Lp[r] += e;
        P[bufp * 2304 + pkg + (4 * g + r) * 72 + kcol] = f2bf(e);
      }
    }
    // PV for tile t
    __builtin_amdgcn_s_setprio(1);
#pragma unroll
    for (int ct2 = 0; ct2 < 2; ++ct2)
#pragma unroll
      for (int ch = 0; ch < 2; ++ch)
        acc[ct2] = __builtin_amdgcn_mfma_f32_16x16x32_bf16(
            pa[ch], vf[ct2 * 2 + ch], acc[ct2], 0, 0, 0);
    __builtin_amdgcn_s_setprio(0);
    __syncthreads();
  }
  // tail: consume tile 31 (buf1), no produce
  {
    const int mrow = (kv0 >> 5) + 62;
    short8 vf[4];
#pragma unroll
    for (int ct2 = 0; ct2 < 2; ++ct2)
#pragma unroll
      for (int ch = 0; ch < 2; ++ch)
        vf[ct2 * 2 + ch] = *(const short8*)&vbase[
            (size_t)(cg * 2 + ct2) * 65536 + (size_t)(mrow + ch) * 512 +
            g * 128 + l15 * 8];
    short8 pa[2];
#pragma unroll
    for (int ch = 0; ch < 2; ++ch)
      pa[ch] = *(const short8*)&P[2304 + pkg + l15 * 72 + ch * 32 + g * 8];
    __builtin_amdgcn_s_setprio(1);
#pragma unroll
    for (int ct2 = 0; ct2 < 2; ++ct2)
#pragma unroll
      for (int ch = 0; ch < 2; ++ch)
        acc[ct2] = __builtin_amdgcn_mfma_f32_16x16x32_bf16(
            pa[ch], vf[ct2 * 2 + ch], acc[ct2], 0, 0, 0);
    __builtin_amdgcn_s_setprio(0);
  }

  // intra-wave L reduce over the 16 key-columns
#pragma unroll
  for (int r = 0; r < 4; ++r) {
    float v = Lp[r];
    v += __shfl_xor(v, 1);
    v += __shfl_xor(v, 2);
    v += __shfl_xor(v, 4);
    v += __shfl_xor(v, 8);
    Lp[r] = v;
  }
  if (l15 == 0) {
    f32x4 lv;
    lv[0] = Lp[0]; lv[1] = Lp[1]; lv[2] = Lp[2]; lv[3] = Lp[3];
    *(f32x4*)&LDp[w * 16 + 4 * g] = lv;
  }
  __syncthreads();  // also retires all pa reads before P-region reuse

  float* RED = (float*)smem;  // [0,8192): 4 cg slots of 2048 B
  if (kg == 1) {
    *(f32x4*)&RED[cg * 512 + lane * 4] = acc[0];
    *(f32x4*)&RED[cg * 512 + 256 + lane * 4] = acc[1];
  }
  __syncthreads();

  if (kg == 0) {
    acc[0] += *(const f32x4*)&RED[cg * 512 + lane * 4];
    acc[1] += *(const f32x4*)&RED[cg * 512 + 256 + lane * 4];
    f32x4 Lt = {};
#pragma unroll
    for (int w8 = 0; w8 < 8; ++w8)
      Lt += *(const f32x4*)&LDp[w8 * 16 + 4 * g];
    const float ga = gamma[0];
    f32x4 inv;
#pragma unroll
    for (int r = 0; r < 4; ++r) inv[r] = 1.0f / Lt[r];

    const float* xb = x + (size_t)b * CDIM * NTOK;
    float* ob = out + (size_t)b * CDIM * NTOK;
#pragma unroll
    for (int ct2 = 0; ct2 < 2; ++ct2) {
      int c = cg * 32 + ct2 * 16 + l15;
      size_t idx = (size_t)c * NTOK + q0 + 4 * g;
      f32x4 xv = *(const f32x4*)&xb[idx];
      f32x4 o;
#pragma unroll
      for (int r = 0; r < 4; ++r)
        o[r] = ga * acc[ct2][r] * inv[r] + xv[r];
      *(f32x4*)&ob[idx] = o;
    }
  }
}

extern "C" void kernel_launch(void* const* d_in, const int* in_sizes, int n_in,
                              void* d_out, int out_size, void* d_ws, size_t ws_size,
                              hipStream_t stream) {
  const float* x     = (const float*)d_in[0];
  const float* Wq    = (const float*)d_in[1];
  const float* bq    = (const float*)d_in[2];
  const float* Wk    = (const float*)d_in[3];
  const float* bk    = (const float*)d_in[4];
  const float* Wv    = (const float*)d_in[5];
  const float* bv    = (const float*)d_in[6];
  const float* gamma = (const float*)d_in[7];

  unsigned short* qb = (unsigned short*)d_ws;          // 512 KB
  unsigned short* kb = qb + (size_t)4 * NTOK * 16;     // 512 KB
  unsigned short* vb = kb + (size_t)4 * NTOK * 16;     // 4 MB (tiled layout)
  float* outp = (float*)d_out;

  sa3d_proj<<<dim3(256), dim3(256), 0, stream>>>(x, Wq, bq, Wk, bk, Wv, bv,
                                                 qb, kb, vb);
  sa3d_attn<<<dim3(1024), dim3(512), 0, stream>>>(qb, kb, vb, x, gamma, outp);
}